// Round 5
// baseline (1132.567 us; speedup 1.0000x reference)
//
#include <hip/hip_runtime.h>
#include <hip/hip_bf16.h>

// Problem constants
#define BATCH 32
#define CCH   512
#define HWSZ  1024
#define RCH   256

typedef __attribute__((ext_vector_type(8))) _Float16 f16x8;
typedef __attribute__((ext_vector_type(4))) float f32x4;

__device__ __forceinline__ ushort f2h(float f) {
    _Float16 h = (_Float16)f;
    ushort u; __builtin_memcpy(&u, &h, 2);
    return u;
}

__device__ __forceinline__ void load_lds16(const void* g, void* l) {
    __builtin_amdgcn_global_load_lds((const __attribute__((address_space(1))) void*)g,
                                     (__attribute__((address_space(3))) void*)l,
                                     16, 0, 0);
}

// T1: bijective XCD-aware block swizzle (all grids divisible by 8)
__device__ __forceinline__ void xcd_swizzle(int& bx, int& by, int& bz) {
    int gx = gridDim.x, gy = gridDim.y;
    int n   = gx * gy * gridDim.z;
    int lin = bx + gx * (by + gy * bz);
    int cpx = n >> 3;
    int s = (lin & 7) * cpx + (lin >> 3);
    bx = s % gx; s /= gx;
    by = s % gy;
    bz = s / gy;
}

// ---------------- weight prep: Wk||Wp -> fp16, Wv -> fp16, stack biases
__global__ __launch_bounds__(256) void k_prep_w(
    const float* __restrict__ Wk, const float* __restrict__ bk,
    const float* __restrict__ Wp, const float* __restrict__ bp,
    const float* __restrict__ Wv,
    ushort* __restrict__ Wkp_h, ushort* __restrict__ Wv_h, float* __restrict__ bias_kp)
{
    int idx = blockIdx.x * 256 + threadIdx.x;   // over 512*512
    if (idx < 512 * 512) {
        int o = idx >> 9, c = idx & 511;
        float w = (o < 256) ? Wk[o * 512 + c] : Wp[(o - 256) * 512 + c];
        Wkp_h[idx] = f2h(w);
        Wv_h[idx]  = f2h(Wv[idx]);
        if (c == 0) bias_kp[o] = (o < 256) ? bk[o] : bp[o - 256];
    }
}

// ---------------- transpose: x[b][c][n] fp32 -> xt[b][n][c] fp16
__global__ __launch_bounds__(256) void k_transpose(
    const float* __restrict__ x, ushort* __restrict__ xt)
{
    __shared__ float tile[64][65];
    int b  = blockIdx.z;
    int c0 = blockIdx.y * 64;
    int n0 = blockIdx.x * 64;
    const float* xb = x + (size_t)b * CCH * HWSZ;
    int t  = threadIdx.x;
    int tq = t >> 6;      // 0..3
    int tl = t & 63;      // 0..63
    #pragma unroll
    for (int i = 0; i < 16; ++i) {
        int c = i * 4 + tq;
        tile[c][tl] = xb[(size_t)(c0 + c) * HWSZ + n0 + tl];
    }
    __syncthreads();
    ushort* oh = xt + (size_t)b * HWSZ * CCH;
    #pragma unroll
    for (int i = 0; i < 16; ++i) {
        int n = i * 4 + tq;
        oh[(size_t)(n0 + n) * CCH + c0 + tl] = f2h(tile[tl][n]);
    }
}

// ================= 256x256 GEMM, BK=32, 64KiB LDS (2 blocks/CU): out = A*B^T
// Two 16KiB slots per operand rotate with 1-slice lookahead; per slice:
// stage next slice (4 glds), 12 ds_reads, 32 MFMA in 2 waits, vmcnt(0)+barrier.
// Cross-block overlap (2 blocks/CU) hides the per-slice waits.
template<int MODE>
__global__ __launch_bounds__(512, 4) void k_gemm32(
    const ushort* __restrict__ A, const ushort* __restrict__ B,
    int lda, int ldb, long aBatch, long bBatch,
    float* __restrict__ outF, ushort* __restrict__ out16,
    long oBatch, int ldo,
    const float* __restrict__ bias,
    const float* __restrict__ xres, const float* __restrict__ param,
    int NT)
{
    __shared__ ushort lds[2][2][8192];   // [slot][op], 64 KiB; slot = 256 rows x 32 cols
    int bx = blockIdx.x, by = blockIdx.y, bz = blockIdx.z;
    xcd_swizzle(bx, by, bz);
    const int z  = bz;
    const int m0 = bx * 256;
    const int n0 = by * 256;
    const int t    = threadIdx.x;
    const int lane = t & 63;
    const int w    = t >> 6;
    const int wm = w >> 2, wn = w & 3;      // 2 x 4 wave grid
    const int l15 = lane & 15;
    const int G   = (lane >> 4) ^ ((lane >> 1) & 3);  // read-side granule swizzle

    const ushort* Ab = A + (size_t)z * aBatch;
    const ushort* Bb = B + (size_t)z * bBatch;

    // staging: thread t covers rows sr and sr+128, granule sg (write-side swizzle
    // folded into the global source address; LDS dest stays linear)
    const int sr = t >> 2;
    const int sg = (t & 3) ^ ((t >> 3) & 3);

    f32x4 acc[8][4] = {};
    f16x8 a[8], b01[2], b23[2];

#define STAGE(slot, op, s) do {                                              \
        const ushort* gb_ = (op) ? Bb : Ab;                                  \
        int ld_ = (op) ? ldb : lda;                                          \
        int r0_ = (op) ? n0 : m0;                                            \
        size_t src_ = (size_t)(r0_ + sr) * ld_ + (s) * 32 + sg * 8;          \
        load_lds16(gb_ + src_, &lds[slot][op][t * 8]);                       \
        load_lds16(gb_ + src_ + (size_t)128 * ld_, &lds[slot][op][t * 8 + 4096]); \
    } while (0)

#define RD_A(slot) do {                                                      \
        _Pragma("unroll")                                                    \
        for (int mi = 0; mi < 8; ++mi)                                       \
            a[mi] = *(const f16x8*)&lds[slot][0][(wm * 128 + mi * 16 + l15) * 32 + G * 8]; \
    } while (0)

#define RD_B(dst, slot, nh) do {                                             \
        _Pragma("unroll")                                                    \
        for (int ni = 0; ni < 2; ++ni)                                       \
            dst[ni] = *(const f16x8*)&lds[slot][1][(wn * 64 + (nh) * 32 + ni * 16 + l15) * 32 + G * 8]; \
    } while (0)

#define BAR() __builtin_amdgcn_s_barrier()
#define WAIT_LGKM(N) do { asm volatile("s_waitcnt lgkmcnt(" #N ")" ::: "memory"); \
                          __builtin_amdgcn_sched_barrier(0); } while (0)
#define WAIT_VM(N)   do { asm volatile("s_waitcnt vmcnt(" #N ")" ::: "memory"); } while (0)

#define MFMA16(bv, nh) do {                                                  \
        __builtin_amdgcn_s_setprio(1);                                       \
        _Pragma("unroll")                                                    \
        for (int mi = 0; mi < 8; ++mi) {                                     \
            acc[mi][(nh)*2+0] = __builtin_amdgcn_mfma_f32_16x16x32_f16(a[mi], bv[0], acc[mi][(nh)*2+0], 0, 0, 0); \
            acc[mi][(nh)*2+1] = __builtin_amdgcn_mfma_f32_16x16x32_f16(a[mi], bv[1], acc[mi][(nh)*2+1], 0, 0, 0); \
        }                                                                    \
        __builtin_amdgcn_s_setprio(0);                                       \
    } while (0)

// One 32-wide K-slice. ST=1: stage slice s+1 into slot^1, fence it at the end.
#define SLICE(slot, s, ST) do {                                              \
        if (ST) { STAGE((slot) ^ 1, 0, (s) + 1); STAGE((slot) ^ 1, 1, (s) + 1); } \
        RD_A(slot); RD_B(b01, slot, 0); RD_B(b23, slot, 1);                  \
        WAIT_LGKM(2);                                                        \
        MFMA16(b01, 0);                                                      \
        WAIT_LGKM(0);                                                        \
        MFMA16(b23, 1);                                                      \
        if (ST) { WAIT_VM(0); }                                              \
        BAR();                                                               \
    } while (0)

    // prologue: stage slice 0 into slot 0
    STAGE(0, 0, 0); STAGE(0, 1, 0);
    WAIT_VM(0);
    BAR();

    // slices 0..NT-2 stage their successor; NT-1 is odd for all callers
    const int half = (NT - 1) >> 1;
    for (int jj = 0; jj < half; ++jj) {
        SLICE(0, 2 * jj, 1);
        SLICE(1, 2 * jj + 1, 1);
    }
    SLICE(0, NT - 2, 1);    // stages final slice NT-1 into slot 1
    SLICE(1, 0, 0);         // final slice, no staging

    // ---------------- epilogue
    const float prm = (MODE == 3) ? param[0] : 0.f;
    #pragma unroll
    for (int mi = 0; mi < 8; ++mi) {
        #pragma unroll
        for (int ni = 0; ni < 4; ++ni) {
            int gc  = n0 + wn * 64 + (ni >> 1) * 32 + (ni & 1) * 16 + l15;
            int gr0 = m0 + wm * 128 + mi * 16 + (lane >> 4) * 4;
            if (MODE == 3) {
                float*       ob = outF + (size_t)z * oBatch;
                const float* xb = xres + (size_t)z * oBatch;
                size_t g = (size_t)gc * ldo + gr0;
                float4 xv = *(const float4*)&xb[g];
                float4 ov;
                ov.x = xv.x + acc[mi][ni][0] * prm;
                ov.y = xv.y + acc[mi][ni][1] * prm;
                ov.z = xv.z + acc[mi][ni][2] * prm;
                ov.w = xv.w + acc[mi][ni][3] * prm;
                *(float4*)&ob[g] = ov;
            } else {
                #pragma unroll
                for (int jj = 0; jj < 4; ++jj) {
                    int gr = gr0 + jj;
                    float v = acc[mi][ni][jj];
                    if (MODE == 0) {
                        v += bias[gc];
                        out16[(size_t)gr * ldo + gc] = f2h(v);
                    } else if (MODE == 1) {
                        v += bias[gr];
                        out16[(size_t)z * oBatch + (size_t)gr * ldo + gc] = f2h(v);
                    } else { // MODE 2
                        outF[(size_t)z * oBatch + (size_t)gr * ldo + gc] = v;
                    }
                }
            }
        }
    }
#undef STAGE
#undef RD_A
#undef RD_B
#undef BAR
#undef WAIT_LGKM
#undef WAIT_VM
#undef MFMA16
#undef SLICE
}

// ---------------- row softmax over E (fp32), write sim fp16 in-place over row start
__global__ __launch_bounds__(256) void k_softmax(float* __restrict__ E)
{
    int blk = blockIdx.x;            // b*1024 + n
    float* row = E + (size_t)blk * HWSZ;
    int t = threadIdx.x;
    float4 v = *(const float4*)&row[t * 4];
    float mx = fmaxf(fmaxf(v.x, v.y), fmaxf(v.z, v.w));
    #pragma unroll
    for (int off = 1; off < 64; off <<= 1)
        mx = fmaxf(mx, __shfl_xor(mx, off));
    __shared__ float redm[4];
    __shared__ float reds[4];
    int lane = t & 63, wv = t >> 6;
    if (lane == 0) redm[wv] = mx;
    __syncthreads();
    mx = fmaxf(fmaxf(redm[0], redm[1]), fmaxf(redm[2], redm[3]));
    float e0 = __expf(v.x - mx), e1 = __expf(v.y - mx);
    float e2 = __expf(v.z - mx), e3 = __expf(v.w - mx);
    float s = (e0 + e1) + (e2 + e3);
    #pragma unroll
    for (int off = 1; off < 64; off <<= 1)
        s += __shfl_xor(s, off);
    if (lane == 0) reds[wv] = s;
    __syncthreads();
    s = (reds[0] + reds[1]) + (reds[2] + reds[3]);
    float inv = 1.0f / s;
    ushort4 o;
    o.x = f2h(e0 * inv); o.y = f2h(e1 * inv);
    o.z = f2h(e2 * inv); o.w = f2h(e3 * inv);
    *(ushort4*)((ushort*)row + t * 4) = o;
}

extern "C" void kernel_launch(void* const* d_in, const int* in_sizes, int n_in,
                              void* d_out, int out_size, void* d_ws, size_t ws_size,
                              hipStream_t stream)
{
    const float* x    = (const float*)d_in[0];
    const float* Wk   = (const float*)d_in[1];
    const float* bk   = (const float*)d_in[2];
    const float* Wp   = (const float*)d_in[3];
    const float* bp   = (const float*)d_in[4];
    const float* Wv   = (const float*)d_in[5];
    const float* bv   = (const float*)d_in[6];
    const float* prm  = (const float*)d_in[7];
    float* out = (float*)d_out;
    char* ws = (char*)d_ws;

    // workspace layout (bytes)
    const size_t SZ16 = (size_t)BATCH * HWSZ * CCH * 2;   // 33.55 MB
    ushort* xt    = (ushort*)(ws + 0);
    ushort* KPt   = (ushort*)(ws + SZ16);
    ushort* fv    = (ushort*)(ws + 2 * SZ16);
    float*  E     = (float*)(ws + 3 * SZ16);              // 134.2 MB
    char* wbase   = ws + 3 * SZ16 + (size_t)BATCH * HWSZ * HWSZ * 4;
    ushort* Wkp_h = (ushort*)(wbase);
    ushort* Wv_h  = (ushort*)(wbase + 524288);
    float*  bias_kp = (float*)(wbase + 2 * 524288);

    // 1) weight prep + x transpose
    k_prep_w<<<1024, 256, 0, stream>>>(Wk, bk, Wp, bp, Wv, Wkp_h, Wv_h, bias_kp);
    k_transpose<<<dim3(16, 8, 32), 256, 0, stream>>>(x, xt);

    // 2) key/prod projection: KPt[32768,512] = xt[32768,512] * Wkp[512,512]^T
    k_gemm32<0><<<dim3(128, 2, 1), 512, 0, stream>>>(
        xt, Wkp_h, CCH, CCH, 0, 0,
        nullptr, KPt, 0, CCH,
        bias_kp, nullptr, nullptr, CCH / 32);

    // 3) value projection: fv[b][o][m] = Wv[o][c] * xt[b][m][c]^T
    k_gemm32<1><<<dim3(2, 4, 32), 512, 0, stream>>>(
        Wv_h, xt, CCH, CCH, 0, (long)HWSZ * CCH,
        nullptr, fv, (long)CCH * HWSZ, HWSZ,
        bv, nullptr, nullptr, CCH / 32);

    // 4) energy: E[b][n][m] = Kt[b][n][r] * Pt[b][m][r]^T  (K cols 0..255, P cols 256..511)
    k_gemm32<2><<<dim3(4, 4, 32), 512, 0, stream>>>(
        KPt, KPt + RCH, CCH, CCH,
        (long)HWSZ * CCH, (long)HWSZ * CCH,
        E, nullptr, (long)HWSZ * HWSZ, HWSZ,
        nullptr, nullptr, nullptr, RCH / 32);

    // 5) softmax rows -> sim fp16 (in-place over E rows; row stride stays 4096 B)
    k_softmax<<<BATCH * HWSZ, 256, 0, stream>>>(E);

    // 6) PV + residual: att^T[n][c] = sim[n][m] * fv[c][m]^T ; out = x + att*param
    k_gemm32<3><<<dim3(4, 2, 32), 512, 0, stream>>>(
        (const ushort*)E, fv, 2048, HWSZ,
        (long)HWSZ * 2048, (long)CCH * HWSZ,
        out, nullptr, (long)CCH * HWSZ, HWSZ,
        nullptr, x, prm, HWSZ / 32);
}

// Round 6
// 196.768 us; speedup vs baseline: 5.7559x; 5.7559x over previous
//
#include <hip/hip_runtime.h>
#include <hip/hip_bf16.h>

// Problem constants
#define BATCH 32
#define CCH   512
#define HWSZ  1024
#define RCH   256

typedef __attribute__((ext_vector_type(8))) _Float16 f16x8;
typedef __attribute__((ext_vector_type(4))) float f32x4;

__device__ __forceinline__ ushort f2h(float f) {
    _Float16 h = (_Float16)f;
    ushort u; __builtin_memcpy(&u, &h, 2);
    return u;
}
__device__ __forceinline__ float h2f(ushort u) {
    _Float16 h; __builtin_memcpy(&h, &u, 2);
    return (float)h;
}

__device__ __forceinline__ void load_lds16(const void* g, void* l) {
    __builtin_amdgcn_global_load_lds((const __attribute__((address_space(1))) void*)g,
                                     (__attribute__((address_space(3))) void*)l,
                                     16, 0, 0);
}

// T1: bijective XCD-aware block swizzle (all grids divisible by 8)
__device__ __forceinline__ void xcd_swizzle(int& bx, int& by, int& bz) {
    int gx = gridDim.x, gy = gridDim.y;
    int n   = gx * gy * gridDim.z;
    int lin = bx + gx * (by + gy * bz);
    int cpx = n >> 3;
    int s = (lin & 7) * cpx + (lin >> 3);
    bx = s % gx; s /= gx;
    by = s % gy;
    bz = s / gy;
}

// ---------------- weight prep: Wk||Wp -> fp16, Wv -> fp16, stack biases
__global__ __launch_bounds__(256) void k_prep_w(
    const float* __restrict__ Wk, const float* __restrict__ bk,
    const float* __restrict__ Wp, const float* __restrict__ bp,
    const float* __restrict__ Wv,
    ushort* __restrict__ Wkp_h, ushort* __restrict__ Wv_h, float* __restrict__ bias_kp)
{
    int idx = blockIdx.x * 256 + threadIdx.x;   // over 512*512
    if (idx < 512 * 512) {
        int o = idx >> 9, c = idx & 511;
        float w = (o < 256) ? Wk[o * 512 + c] : Wp[(o - 256) * 512 + c];
        Wkp_h[idx] = f2h(w);
        Wv_h[idx]  = f2h(Wv[idx]);
        if (c == 0) bias_kp[o] = (o < 256) ? bk[o] : bp[o - 256];
    }
}

// ---------------- transpose: x[b][c][n] fp32 -> xt[b][n][c] fp16
__global__ __launch_bounds__(256) void k_transpose(
    const float* __restrict__ x, ushort* __restrict__ xt)
{
    __shared__ float tile[64][65];
    int b  = blockIdx.z;
    int c0 = blockIdx.y * 64;
    int n0 = blockIdx.x * 64;
    const float* xb = x + (size_t)b * CCH * HWSZ;
    int t  = threadIdx.x;
    int tq = t >> 6;      // 0..3
    int tl = t & 63;      // 0..63
    #pragma unroll
    for (int i = 0; i < 16; ++i) {
        int c = i * 4 + tq;
        tile[c][tl] = xb[(size_t)(c0 + c) * HWSZ + n0 + tl];
    }
    __syncthreads();
    ushort* oh = xt + (size_t)b * HWSZ * CCH;
    #pragma unroll
    for (int i = 0; i < 16; ++i) {
        int n = i * 4 + tq;
        oh[(size_t)(n0 + n) * CCH + c0 + tl] = f2h(tile[tl][n]);
    }
}

// ================= 256x256 8-phase GEMM: out = A[M,K] * B[N,K]^T (fp16, fp32 acc)
// MODE 0: KP-projection (+col bias, fp16 out)   MODE 1: V-projection (+row bias, fp16 out)
// MODE 2: energy (fp16 out)                     MODE 3: PV (out = x + acc*param, transposed)
template<int MODE>
__global__ __launch_bounds__(512, 2) void k_gemm8(
    const ushort* __restrict__ A, const ushort* __restrict__ B,
    int lda, int ldb, long aBatch, long bBatch,
    float* __restrict__ outF, ushort* __restrict__ out16,
    long oBatch, int ldo,
    const float* __restrict__ bias,
    const float* __restrict__ xres, const float* __restrict__ param,
    int NT)
{
    __shared__ ushort lds[2][2][2][8192];   // 128 KiB
    int bx = blockIdx.x, by = blockIdx.y, bz = blockIdx.z;
    xcd_swizzle(bx, by, bz);
    const int z  = bz;
    const int m0 = bx * 256;
    const int n0 = by * 256;
    const int t    = threadIdx.x;
    const int lane = t & 63;
    const int w    = t >> 6;
    const int wm = w >> 2, wn = w & 3;      // 2 x 4 wave grid
    const int l15 = lane & 15;
    const int G   = (lane >> 4) ^ ((lane >> 1) & 3);  // read-side granule swizzle

    const ushort* Ab = A + (size_t)z * aBatch;
    const ushort* Bb = B + (size_t)z * bBatch;

    // staging constants: thread t covers row sr (i=0) and sr+128 (i=1), granule sg
    const int sr = t >> 2;
    const int sg = (t & 3) ^ ((t >> 3) & 3);

    f32x4 acc[8][4] = {};
    f16x8 a[8], b[2];

#define STAGE(par, op, ks, kt) do {                                          \
        const ushort* gb_ = (op) ? Bb : Ab;                                  \
        int ld_ = (op) ? ldb : lda;                                          \
        int r0_ = (op) ? n0 : m0;                                            \
        size_t src_ = (size_t)(r0_ + sr) * ld_ + (kt) * 64 + (ks) * 32 + sg * 8; \
        load_lds16(gb_ + src_, &lds[par][op][ks][t * 8]);                    \
        load_lds16(gb_ + src_ + (size_t)128 * ld_, &lds[par][op][ks][t * 8 + 4096]); \
    } while (0)

#define LDA_(cur, ks) do {                                                   \
        _Pragma("unroll")                                                    \
        for (int mi = 0; mi < 8; ++mi)                                       \
            a[mi] = *(const f16x8*)&lds[cur][0][ks][(wm * 128 + mi * 16 + l15) * 32 + G * 8]; \
    } while (0)

#define LDB_(cur, ks, nh) do {                                               \
        _Pragma("unroll")                                                    \
        for (int ni = 0; ni < 2; ++ni)                                       \
            b[ni] = *(const f16x8*)&lds[cur][1][ks][(wn * 64 + (nh) * 32 + ni * 16 + l15) * 32 + G * 8]; \
    } while (0)

#define BAR() __builtin_amdgcn_s_barrier()

#define MFMA_BLK(nh) do {                                                    \
        asm volatile("s_waitcnt lgkmcnt(0)" ::: "memory");                   \
        __builtin_amdgcn_sched_barrier(0);                                   \
        __builtin_amdgcn_s_setprio(1);                                       \
        _Pragma("unroll")                                                    \
        for (int mi = 0; mi < 8; ++mi) {                                     \
            acc[mi][(nh)*2+0] = __builtin_amdgcn_mfma_f32_16x16x32_f16(a[mi], b[0], acc[mi][(nh)*2+0], 0, 0, 0); \
            acc[mi][(nh)*2+1] = __builtin_amdgcn_mfma_f32_16x16x32_f16(a[mi], b[1], acc[mi][(nh)*2+1], 0, 0, 0); \
        }                                                                    \
        __builtin_amdgcn_s_setprio(0);                                       \
    } while (0)

    // prologue: stage all 4 halves of K-tile 0
    STAGE(0, 0, 0, 0); STAGE(0, 1, 0, 0); STAGE(0, 0, 1, 0); STAGE(0, 1, 1, 0);
    asm volatile("s_waitcnt vmcnt(4)" ::: "memory");   // A0(0),B0(0) landed
    BAR();

    for (int j = 0; j < NT - 1; ++j) {
        int cur = j & 1, nxt = cur ^ 1;
        // q0 (ks=0, nh=0)
        STAGE(nxt, 0, 0, j + 1);
        LDA_(cur, 0); LDB_(cur, 0, 0);
        BAR();
        MFMA_BLK(0);
        BAR();
        // q1 (ks=0, nh=1)
        STAGE(nxt, 1, 0, j + 1);
        LDB_(cur, 0, 1);
        BAR();
        MFMA_BLK(1);
        asm volatile("s_waitcnt vmcnt(4)" ::: "memory");   // A1(j),B1(j) landed (all waves)
        BAR();
        // q2 (ks=1, nh=0)
        STAGE(nxt, 0, 1, j + 1);
        LDA_(cur, 1); LDB_(cur, 1, 0);
        BAR();
        MFMA_BLK(0);
        BAR();
        // q3 (ks=1, nh=1)
        STAGE(nxt, 1, 1, j + 1);
        LDB_(cur, 1, 1);
        BAR();
        MFMA_BLK(1);
        asm volatile("s_waitcnt vmcnt(4)" ::: "memory");   // A0(j+1),B0(j+1) landed
        BAR();
    }
    // last K-tile (no staging)
    {
        int cur = (NT - 1) & 1;
        LDA_(cur, 0); LDB_(cur, 0, 0);
        BAR();
        MFMA_BLK(0);
        BAR();
        LDB_(cur, 0, 1);
        BAR();
        MFMA_BLK(1);
        asm volatile("s_waitcnt vmcnt(0)" ::: "memory");   // A1,B1 landed
        BAR();
        LDA_(cur, 1); LDB_(cur, 1, 0);
        BAR();
        MFMA_BLK(0);
        BAR();
        LDB_(cur, 1, 1);
        BAR();
        MFMA_BLK(1);
    }

    // ---------------- epilogue
    const float prm = (MODE == 3) ? param[0] : 0.f;
    #pragma unroll
    for (int mi = 0; mi < 8; ++mi) {
        #pragma unroll
        for (int ni = 0; ni < 4; ++ni) {
            int gc  = n0 + wn * 64 + (ni >> 1) * 32 + (ni & 1) * 16 + l15;
            int gr0 = m0 + wm * 128 + mi * 16 + (lane >> 4) * 4;
            if (MODE == 3) {
                float*       ob = outF + (size_t)z * oBatch;
                const float* xb = xres + (size_t)z * oBatch;
                size_t g = (size_t)gc * ldo + gr0;
                float4 xv = *(const float4*)&xb[g];
                float4 ov;
                ov.x = xv.x + acc[mi][ni][0] * prm;
                ov.y = xv.y + acc[mi][ni][1] * prm;
                ov.z = xv.z + acc[mi][ni][2] * prm;
                ov.w = xv.w + acc[mi][ni][3] * prm;
                *(float4*)&ob[g] = ov;
            } else {
                #pragma unroll
                for (int jj = 0; jj < 4; ++jj) {
                    int gr = gr0 + jj;
                    float v = acc[mi][ni][jj];
                    if (MODE == 0) {
                        v += bias[gc];
                        out16[(size_t)gr * ldo + gc] = f2h(v);
                    } else if (MODE == 1) {
                        v += bias[gr];
                        out16[(size_t)z * oBatch + (size_t)gr * ldo + gc] = f2h(v);
                    } else { // MODE 2: energy -> fp16
                        out16[(size_t)z * oBatch + (size_t)gr * ldo + gc] = f2h(v);
                    }
                }
            }
        }
    }
#undef STAGE
#undef LDA_
#undef LDB_
#undef BAR
#undef MFMA_BLK
}

// ---------------- row softmax over E (fp16 in, fp16 sim out, in place)
__global__ __launch_bounds__(256) void k_softmax(ushort* __restrict__ E)
{
    int blk = blockIdx.x;            // b*1024 + n
    ushort* row = E + (size_t)blk * HWSZ;
    int t = threadIdx.x;
    ushort4 u = *(const ushort4*)&row[t * 4];
    float v0 = h2f(u.x), v1 = h2f(u.y), v2 = h2f(u.z), v3 = h2f(u.w);
    float mx = fmaxf(fmaxf(v0, v1), fmaxf(v2, v3));
    #pragma unroll
    for (int off = 1; off < 64; off <<= 1)
        mx = fmaxf(mx, __shfl_xor(mx, off));
    __shared__ float redm[4];
    __shared__ float reds[4];
    int lane = t & 63, wv = t >> 6;
    if (lane == 0) redm[wv] = mx;
    __syncthreads();
    mx = fmaxf(fmaxf(redm[0], redm[1]), fmaxf(redm[2], redm[3]));
    float e0 = __expf(v0 - mx), e1 = __expf(v1 - mx);
    float e2 = __expf(v2 - mx), e3 = __expf(v3 - mx);
    float s = (e0 + e1) + (e2 + e3);
    #pragma unroll
    for (int off = 1; off < 64; off <<= 1)
        s += __shfl_xor(s, off);
    if (lane == 0) reds[wv] = s;
    __syncthreads();
    s = (reds[0] + reds[1]) + (reds[2] + reds[3]);
    float inv = 1.0f / s;
    ushort4 o;
    o.x = f2h(e0 * inv); o.y = f2h(e1 * inv);
    o.z = f2h(e2 * inv); o.w = f2h(e3 * inv);
    *(ushort4*)&row[t * 4] = o;
}

extern "C" void kernel_launch(void* const* d_in, const int* in_sizes, int n_in,
                              void* d_out, int out_size, void* d_ws, size_t ws_size,
                              hipStream_t stream)
{
    const float* x    = (const float*)d_in[0];
    const float* Wk   = (const float*)d_in[1];
    const float* bk   = (const float*)d_in[2];
    const float* Wp   = (const float*)d_in[3];
    const float* bp   = (const float*)d_in[4];
    const float* Wv   = (const float*)d_in[5];
    const float* bv   = (const float*)d_in[6];
    const float* prm  = (const float*)d_in[7];
    float* out = (float*)d_out;
    char* ws = (char*)d_ws;

    // workspace layout (bytes)
    const size_t SZ16 = (size_t)BATCH * HWSZ * CCH * 2;   // 33.55 MB
    ushort* xt    = (ushort*)(ws + 0);
    ushort* KPt   = (ushort*)(ws + SZ16);
    ushort* fv    = (ushort*)(ws + 2 * SZ16);
    ushort* E     = (ushort*)(ws + 3 * SZ16);             // fp16, 67.1 MB
    char* wbase   = ws + 3 * SZ16 + (size_t)BATCH * HWSZ * HWSZ * 2;
    ushort* Wkp_h = (ushort*)(wbase);
    ushort* Wv_h  = (ushort*)(wbase + 524288);
    float*  bias_kp = (float*)(wbase + 2 * 524288);

    // 1) weight prep + x transpose
    k_prep_w<<<1024, 256, 0, stream>>>(Wk, bk, Wp, bp, Wv, Wkp_h, Wv_h, bias_kp);
    k_transpose<<<dim3(16, 8, 32), 256, 0, stream>>>(x, xt);

    // 2) key/prod projection: KPt[32768,512] = xt[32768,512] * Wkp[512,512]^T
    k_gemm8<0><<<dim3(128, 2, 1), 512, 0, stream>>>(
        xt, Wkp_h, CCH, CCH, 0, 0,
        nullptr, KPt, 0, CCH,
        bias_kp, nullptr, nullptr, CCH / 64);

    // 3) value projection: fv[b][o][m] = Wv[o][c] * xt[b][m][c]^T
    k_gemm8<1><<<dim3(2, 4, 32), 512, 0, stream>>>(
        Wv_h, xt, CCH, CCH, 0, (long)HWSZ * CCH,
        nullptr, fv, (long)CCH * HWSZ, HWSZ,
        bv, nullptr, nullptr, CCH / 64);

    // 4) energy: E[b][n][m] = Kt[b][n][r] * Pt[b][m][r]^T  (fp16 out)
    k_gemm8<2><<<dim3(4, 4, 32), 512, 0, stream>>>(
        KPt, KPt + RCH, CCH, CCH,
        (long)HWSZ * CCH, (long)HWSZ * CCH,
        nullptr, E, (long)HWSZ * HWSZ, HWSZ,
        nullptr, nullptr, nullptr, RCH / 64);

    // 5) softmax rows -> sim fp16 (in place)
    k_softmax<<<BATCH * HWSZ, 256, 0, stream>>>(E);

    // 6) PV + residual: att^T[n][c] = sim[n][m] * fv[c][m]^T ; out = x + att*param
    k_gemm8<3><<<dim3(4, 2, 32), 512, 0, stream>>>(
        E, fv, HWSZ, HWSZ,
        (long)HWSZ * HWSZ, (long)CCH * HWSZ,
        out, nullptr, (long)CCH * HWSZ, HWSZ,
        nullptr, x, prm, HWSZ / 64);
}